// Round 6
// baseline (511.492 us; speedup 1.0000x reference)
//
#include <hip/hip_runtime.h>

// LSTM_76622216560744: 2-layer LSTM (H=50), B=2048, T=1024, input dim 1.
// R15: phase-skew experiment on R14 (486 us dispatch). The step is
// phase-serialized by the barrier convoy: all 13 waves run identical code,
// so LDS-read / MFMA / trans phases serialize per SIMD (sum ~860 cyc +
// ~280 chain/barrier = 1139-cyc step) while each unit idles 70%.
// setprio alone was null (it reorders same-phase contenders, cannot create
// offset). NEW: waves 4..7 (exactly ONE per SIMD under w%4 round-robin;
// wave 12 = x-staging tail stays undelayed) execute s_sleep(2) (~128 cyc)
// at body entry -> their read+MFMA front lands under group A's trans
// section; per-SIMD MFMA unit and trans unit run concurrently. setprio(1)
// on the MFMA front now has phase diversity to arbitrate (A-trans at prio 0
// vs B-MFMA at prio 1).
// Kept from R14/R13: 13 waves, 1 barrier/step, fp16 MFMA 16x16x32, M=200
// gate rows (row'=unit*4+type), N=16 (8 real batches), K-layout
// [x(0)|h1(1..50)|ONE(51)|h2(52..101)|pad], bias rides const-1.0 k=51 row,
// zacc loop-invariant C operand, weights pre-scaled by -log2e (-2log2e for
// g rows) -> raw v_exp, pre-scaled carry cs=-2log2e*c, fma-form algebra,
// update_dpp L1/L2 merge (row_shr:8, bank 0xC), single-rcp cell
// (5 exp2 + 2 rcp), f16 xs staging, precomputed LDS pointers, frag-ready v
// layout, double-buffered v, invalid lanes write to dump tail.

#define TT 1024
#define HH 50
#define NB 8     // real batches per block
#define NT 832   // 13 waves
#define VSZ 2112 // 2048 data shorts + 64 dump shorts

typedef _Float16 f16x8 __attribute__((ext_vector_type(8)));
typedef unsigned short ushort8 __attribute__((ext_vector_type(8)));
typedef float f32x4 __attribute__((ext_vector_type(4)));

#define NLOG2E  -1.4426950408889634f   // -log2(e)
#define N2LOG2E -2.8853900817779268f   // -2*log2(e)
#define P2LOG2E  2.8853900817779268f   // +2*log2(e)

__device__ __forceinline__ float fast_rcp(float x) { return __builtin_amdgcn_rcpf(x); }
__device__ __forceinline__ float exp2f_hw(float x) { return __builtin_amdgcn_exp2f(x); }
__device__ __forceinline__ unsigned short f16bits(float f) {
    _Float16 h = (_Float16)f;                 // v_cvt_f16_f32 (RNE)
    return __builtin_bit_cast(unsigned short, h);
}
__device__ __forceinline__ float f16tof(unsigned short b) {
    return (float)__builtin_bit_cast(_Float16, b);
}
// merge: per 16-lane row, lanes 0..7 keep a (L1 acc), lanes 8..15 take
// lane-8's b (L2 acc). row_shr:8 = 0x118; bank_mask 0xC enables banks 2,3.
__device__ __forceinline__ float dpp_merge(float a, float b) {
    return __int_as_float(__builtin_amdgcn_update_dpp(
        __float_as_int(a), __float_as_int(b), 0x118, 0xF, 0xC, false));
}

// frag-ready blocked layout: idx = (k>>3)*128 + n*8 + (k&7), k<128, n<16
__device__ __forceinline__ int vidx(int k, int n) {
    return ((k >> 3) << 7) + n * 8 + (k & 7);
}

__global__ __launch_bounds__(NT, 1) void lstm_kernel(
    const float* __restrict__ x,
    const float* __restrict__ W_ih1, const float* __restrict__ W_hh1,
    const float* __restrict__ b_ih1, const float* __restrict__ b_hh1,
    const float* __restrict__ W_ih2, const float* __restrict__ W_hh2,
    const float* __restrict__ b_ih2, const float* __restrict__ b_hh2,
    const float* __restrict__ W_lin, const float* __restrict__ b_lin,
    float* __restrict__ out)
{
    __shared__ unsigned short xs[TT * NB];                            // 16 KB (f16)
    __shared__ __attribute__((aligned(16))) unsigned short v[2][VSZ]; // 8.25 KB

    const int tid  = threadIdx.x;
    const int w    = tid >> 6;       // wave 0..12
    const int L    = tid & 63;
    const int quad = L >> 4;
    const int n15  = L & 15;
    const int b0g  = blockIdx.x * NB;

    const int  m     = w;                // tile per wave
    const int  u     = m * 4 + quad;     // unit this lane updates
    const bool low   = (n15 < NB);       // low half: L1 / B loads
    const bool updOK = (u < HH);
    const bool ldB   = low;
    // phase-skew group B: waves 4..7 (one per SIMD; wave 12 stays in A)
    const bool grpB  = (w >= 4) && (w < 8);
    // wave 12's quad-2 lanes (u=50, update-invalid) stage x(t+1)
    const bool xw    = (w == 12) && (L >= 32) && (L < 32 + NB);
    const int  xb    = L - 32;
    // h slot: low -> h1 (k=1+u), high -> h2 (k=52+u); invalid u -> dump tail
    const int hslot = updOK ? (low ? vidx(1 + u, n15) : vidx(52 + u, n15 - NB))
                            : (2048 + L);

    for (int i = tid; i < 2 * VSZ; i += NT) ((unsigned short*)v)[i] = 0;
    for (int i = tid; i < NB * TT; i += NT) {   // stage x transposed xs[t][b], f16
        int b = i >> 10, t = i & 1023;
        xs[t * NB + b] = f16bits(x[(size_t)b0g * TT + i]);
    }

    // ---- per-wave A-frags: fp16, pre-scaled by -log2e (g rows: -2log2e).
    // Bias rides k=51 (const-1.0 B row) for BOTH layers.
    f16x8 a1[2], a2[4];
    float cs = 0.f;   // carried cell state, PRE-SCALED: cs = -2*log2e * c
                      // (low lanes: layer-1 c, high lanes: layer-2 c)

    {
        const int arow = m * 16 + n15;
        const bool av = (arow < 200);
        const int r = av ? ((arow & 3) * 50 + (arow >> 2)) : 0;  // type*50+unit
        const float sc = ((arow & 3) == 2) ? N2LOG2E : NLOG2E;
        #pragma unroll
        for (int kt = 0; kt < 2; ++kt) {    // L1: k=0 -> W_ih1, 1..50 -> W_hh1, 51 -> bias1
            ushort8 th;
            #pragma unroll
            for (int j = 0; j < 8; ++j) {
                int k = kt * 32 + quad * 8 + j;
                float wv = 0.f;
                if (av) {
                    if (k == 0) wv = W_ih1[r];
                    else if (k <= 50) wv = W_hh1[r * 50 + k - 1];
                    else if (k == 51) wv = b_ih1[r] + b_hh1[r];
                }
                th[j] = f16bits(wv * sc);
            }
            a1[kt] = __builtin_bit_cast(f16x8, th);
        }
        #pragma unroll
        for (int kt = 0; kt < 4; ++kt) {    // L2: 1..50 -> W_ih2, 51 -> bias2, 52..101 -> W_hh2
            ushort8 th;
            #pragma unroll
            for (int j = 0; j < 8; ++j) {
                int k = kt * 32 + quad * 8 + j;
                float wv = 0.f;
                if (av) {
                    if (k >= 1 && k <= 50) wv = W_ih2[r * 50 + k - 1];
                    else if (k == 51) wv = b_ih2[r] + b_hh2[r];
                    else if (k >= 52 && k <= 101) wv = W_hh2[r * 50 + k - 52];
                }
                th[j] = f16bits(wv * sc);
            }
            a2[kt] = __builtin_bit_cast(f16x8, th);
        }
    }

    __syncthreads();
    if (tid < NB) {
        v[0][vidx(0, tid)] = xs[0 * NB + tid];           // x(0), already f16
        const unsigned short one = f16bits(1.0f);        // bias row, both bufs
        v[0][vidx(51, tid)] = one;
        v[1][vidx(51, tid)] = one;
    }
    __syncthreads();

    // ---- precomputed LDS access pointers (one base VGPR + imm offsets) ----
    const f16x8* vr0 = (const f16x8*)(&v[0][0]) + L;   // bfr base, buf 0
    const f16x8* vr1 = (const f16x8*)(&v[1][0]) + L;   // bfr base, buf 1
    unsigned short* hw0 = &v[0][hslot];                // h write, buf 0
    unsigned short* hw1 = &v[1][hslot];                // h write, buf 1
    unsigned short* xp0 = &v[0][vidx(0, xb & 7)];      // x write, buf 0
    unsigned short* xp1 = &v[1][vidx(0, xb & 7)];      // x write, buf 1

    f16x8 bfr[4];
    #pragma unroll
    for (int kt = 0; kt < 4; ++kt)
        bfr[kt] = __builtin_bit_cast(f16x8, ushort8{0,0,0,0,0,0,0,0});

    const f32x4 zacc = {0.f, 0.f, 0.f, 0.f};  // loop-invariant MFMA C operand

    // one step: iter t = L1 gates(t) + L2 gates(t-1); read vrL, write hw/xp.
    // Accumulators hold -g*log2e (g rows: -2g*log2e) -> raw v_exp gives e^-g.
    auto body = [&](int t, const f16x8* vrL, unsigned short* hw,
                    unsigned short* xp, bool doL1, bool doL2,
                    bool masked, bool doX) {
        // phase skew: group B sleeps ~128 cyc so its read+MFMA front runs
        // under group A's trans section (per-SIMD pipe overlap).
        if (grpB) __builtin_amdgcn_s_sleep(2);
        if (doX && xw) *xp = xs[(t + 1) * NB + xb];
        if (ldB) {
            #pragma unroll
            for (int kt = 0; kt < 4; ++kt)
                bfr[kt] = vrL[kt * 64];
        }
        __builtin_amdgcn_s_setprio(1);   // favor waves still in read+MFMA front
        f32x4 aM1 = zacc, aM2 = zacc;
        if (doL2) {     // longer chain (4 dependent, C-forwarded: free) first
            #pragma unroll
            for (int kt = 0; kt < 4; ++kt)
                aM2 = __builtin_amdgcn_mfma_f32_16x16x32_f16(a2[kt], bfr[kt], aM2, 0, 0, 0);
        }
        if (doL1) {
            #pragma unroll
            for (int kt = 0; kt < 2; ++kt)
                aM1 = __builtin_amdgcn_mfma_f32_16x16x32_f16(a1[kt], bfr[kt], aM1, 0, 0, 0);
        }
        __builtin_amdgcn_s_setprio(0);   // trans section runs at base prio
        // merge: low 8 of each 16-row keep L1 acc, high 8 take partner L2 acc
        f32x4 g;
        #pragma unroll
        for (int r = 0; r < 4; ++r) g[r] = dpp_merge(aM1[r], aM2[r]);

        // cell update: g = (-i, -f, -2gg, -o)*log2e (bias included).
        // cs carries -2log2e*c, so ecn = exp2(cs) with no scaling mul.
        if (!masked || (updOK && low)) {
            float ei = exp2f_hw(g[0]);           // e^-i
            float ef = exp2f_hw(g[1]);           // e^-f
            float eg = exp2f_hw(g[2]);           // e^-2gg
            float eo = exp2f_hw(g[3]);           // e^-o
            float ti  = 1.0f + ei;
            float p   = fmaf(ti, eg, ti);        // (1+ei)(1+eg)
            float sgs = fmaf(P2LOG2E, eg, N2LOG2E); // -2log2e*(1-eg)
            float qs  = fmaf(sgs, ef, sgs);      // -2log2e*(1-eg)(1+ef)
            float uu  = 1.0f + ef;
            cs = fmaf(cs, p, qs) * fast_rcp(p * uu); // -2log2e * c_new
            float ecn = exp2f_hw(cs);            // e^-2c
            float to  = 1.0f + eo;
            float den = fmaf(to, ecn, to);       // (1+eo)(1+ecn)
            float h = (1.0f - ecn) * fast_rcp(den);
            *hw = f16bits(h);
        }
        __syncthreads();
    };

    // peel t=0 (no L2 yet: masked update protects high-half cs), steady,
    // then last-x step (t=TT-2 writes x(TT-1)), no-x step, L2-only tail.
    body(0, vr0, hw1, xp1, true, false, true,  true);
    body(1, vr1, hw0, xp0, true, true,  false, true);
    for (int t = 2; t < TT - 2; t += 2) {
        body(t,     vr0, hw1, xp1, true, true, false, true);
        body(t + 1, vr1, hw0, xp0, true, true, false, true);
    }
    body(TT - 2, vr0, hw1, xp1, true,  true, false, true);   // writes x(TT-1)
    body(TT - 1, vr1, hw0, xp0, true,  true, false, false);
    body(TT,     vr0, hw1, xp1, false, true, false, false);  // L2-only tail

    // epilogue: h2(T-1) sits in buf1 slots 52..101
    if (tid < NB) {
        float s = b_lin[0];
        #pragma unroll
        for (int uu = 0; uu < HH; ++uu)
            s += W_lin[uu] * f16tof(v[1][vidx(52 + uu, tid)]);
        out[b0g + tid] = s;
    }
}

extern "C" void kernel_launch(void* const* d_in, const int* in_sizes, int n_in,
                              void* d_out, int out_size, void* d_ws, size_t ws_size,
                              hipStream_t stream) {
    const float* x     = (const float*)d_in[0];
    const float* W_ih1 = (const float*)d_in[1];
    const float* W_hh1 = (const float*)d_in[2];
    const float* b_ih1 = (const float*)d_in[3];
    const float* b_hh1 = (const float*)d_in[4];
    const float* W_ih2 = (const float*)d_in[5];
    const float* W_hh2 = (const float*)d_in[6];
    const float* b_ih2 = (const float*)d_in[7];
    const float* b_hh2 = (const float*)d_in[8];
    const float* W_lin = (const float*)d_in[9];
    const float* b_lin = (const float*)d_in[10];
    float* out = (float*)d_out;

    const int Btot = in_sizes[0] / TT;   // 2048
    const int nblocks = Btot / NB;       // 256 -> 1 block/CU

    lstm_kernel<<<nblocks, NT, 0, stream>>>(
        x, W_ih1, W_hh1, b_ih1, b_hh1, W_ih2, W_hh2, b_ih2, b_hh2,
        W_lin, b_lin, out);
}

// Round 7
// 502.388 us; speedup vs baseline: 1.0181x; 1.0181x over previous
//
#include <hip/hip_runtime.h>

// LSTM_76622216560744: 2-layer LSTM (H=50), B=2048, T=1024, input dim 1.
// R16: exact revert to R14 (measured best: 486 us dispatch / 504 us bench).
// R15's s_sleep phase-skew regressed (+10 us): the per-step barrier
// re-aligns the convoy, so induced skew cannot persist -- it only lengthens
// the slowest wave's path. Structural conclusion (R10/R12/R14/R15 evidence):
// the step is pinned at ~1139 cyc by per-SIMD issue sums (VALU 524 trans-
// floor'd + MFMA 337 floor'd + LDS ~310/CU) under a semantically-required
// all-to-all barrier; every repack (NB=4/16, 2-block, 32x32, fp8) is
// provably issue-negative or numerically unsafe.
// Structure: 13 waves, 1 barrier/step, fp16 MFMA 16x16x32, M=200 gate rows
// (row'=unit*4+type), N=16 (8 real batches), K-layout
// [x(0)|h1(1..50)|ONE(51)|h2(52..101)|pad], bias rides const-1.0 k=51 row,
// zacc loop-invariant C operand, weights pre-scaled by -log2e (-2log2e for
// g rows) -> raw v_exp, pre-scaled carry cs=-2log2e*c, fma-form algebra,
// update_dpp L1/L2 merge (row_shr:8, bank 0xC), single-rcp cell
// (5 exp2 + 2 rcp), f16 xs staging, precomputed LDS pointers, frag-ready v
// layout, double-buffered v, invalid lanes write to dump tail.

#define TT 1024
#define HH 50
#define NB 8     // real batches per block
#define NT 832   // 13 waves
#define VSZ 2112 // 2048 data shorts + 64 dump shorts

typedef _Float16 f16x8 __attribute__((ext_vector_type(8)));
typedef unsigned short ushort8 __attribute__((ext_vector_type(8)));
typedef float f32x4 __attribute__((ext_vector_type(4)));

#define NLOG2E  -1.4426950408889634f   // -log2(e)
#define N2LOG2E -2.8853900817779268f   // -2*log2(e)
#define P2LOG2E  2.8853900817779268f   // +2*log2(e)

__device__ __forceinline__ float fast_rcp(float x) { return __builtin_amdgcn_rcpf(x); }
__device__ __forceinline__ float exp2f_hw(float x) { return __builtin_amdgcn_exp2f(x); }
__device__ __forceinline__ unsigned short f16bits(float f) {
    _Float16 h = (_Float16)f;                 // v_cvt_f16_f32 (RNE)
    return __builtin_bit_cast(unsigned short, h);
}
__device__ __forceinline__ float f16tof(unsigned short b) {
    return (float)__builtin_bit_cast(_Float16, b);
}
// merge: per 16-lane row, lanes 0..7 keep a (L1 acc), lanes 8..15 take
// lane-8's b (L2 acc). row_shr:8 = 0x118; bank_mask 0xC enables banks 2,3.
__device__ __forceinline__ float dpp_merge(float a, float b) {
    return __int_as_float(__builtin_amdgcn_update_dpp(
        __float_as_int(a), __float_as_int(b), 0x118, 0xF, 0xC, false));
}

// frag-ready blocked layout: idx = (k>>3)*128 + n*8 + (k&7), k<128, n<16
__device__ __forceinline__ int vidx(int k, int n) {
    return ((k >> 3) << 7) + n * 8 + (k & 7);
}

__global__ __launch_bounds__(NT, 1) void lstm_kernel(
    const float* __restrict__ x,
    const float* __restrict__ W_ih1, const float* __restrict__ W_hh1,
    const float* __restrict__ b_ih1, const float* __restrict__ b_hh1,
    const float* __restrict__ W_ih2, const float* __restrict__ W_hh2,
    const float* __restrict__ b_ih2, const float* __restrict__ b_hh2,
    const float* __restrict__ W_lin, const float* __restrict__ b_lin,
    float* __restrict__ out)
{
    __shared__ unsigned short xs[TT * NB];                            // 16 KB (f16)
    __shared__ __attribute__((aligned(16))) unsigned short v[2][VSZ]; // 8.25 KB

    const int tid  = threadIdx.x;
    const int w    = tid >> 6;       // wave 0..12
    const int L    = tid & 63;
    const int quad = L >> 4;
    const int n15  = L & 15;
    const int b0g  = blockIdx.x * NB;

    const int  m     = w;                // tile per wave
    const int  u     = m * 4 + quad;     // unit this lane updates
    const bool low   = (n15 < NB);       // low half: L1 / B loads
    const bool updOK = (u < HH);
    const bool ldB   = low;
    // wave 12's quad-2 lanes (u=50, update-invalid) stage x(t+1)
    const bool xw    = (w == 12) && (L >= 32) && (L < 32 + NB);
    const int  xb    = L - 32;
    // h slot: low -> h1 (k=1+u), high -> h2 (k=52+u); invalid u -> dump tail
    const int hslot = updOK ? (low ? vidx(1 + u, n15) : vidx(52 + u, n15 - NB))
                            : (2048 + L);

    for (int i = tid; i < 2 * VSZ; i += NT) ((unsigned short*)v)[i] = 0;
    for (int i = tid; i < NB * TT; i += NT) {   // stage x transposed xs[t][b], f16
        int b = i >> 10, t = i & 1023;
        xs[t * NB + b] = f16bits(x[(size_t)b0g * TT + i]);
    }

    // ---- per-wave A-frags: fp16, pre-scaled by -log2e (g rows: -2log2e).
    // Bias rides k=51 (const-1.0 B row) for BOTH layers.
    f16x8 a1[2], a2[4];
    float cs = 0.f;   // carried cell state, PRE-SCALED: cs = -2*log2e * c
                      // (low lanes: layer-1 c, high lanes: layer-2 c)

    {
        const int arow = m * 16 + n15;
        const bool av = (arow < 200);
        const int r = av ? ((arow & 3) * 50 + (arow >> 2)) : 0;  // type*50+unit
        const float sc = ((arow & 3) == 2) ? N2LOG2E : NLOG2E;
        #pragma unroll
        for (int kt = 0; kt < 2; ++kt) {    // L1: k=0 -> W_ih1, 1..50 -> W_hh1, 51 -> bias1
            ushort8 th;
            #pragma unroll
            for (int j = 0; j < 8; ++j) {
                int k = kt * 32 + quad * 8 + j;
                float wv = 0.f;
                if (av) {
                    if (k == 0) wv = W_ih1[r];
                    else if (k <= 50) wv = W_hh1[r * 50 + k - 1];
                    else if (k == 51) wv = b_ih1[r] + b_hh1[r];
                }
                th[j] = f16bits(wv * sc);
            }
            a1[kt] = __builtin_bit_cast(f16x8, th);
        }
        #pragma unroll
        for (int kt = 0; kt < 4; ++kt) {    // L2: 1..50 -> W_ih2, 51 -> bias2, 52..101 -> W_hh2
            ushort8 th;
            #pragma unroll
            for (int j = 0; j < 8; ++j) {
                int k = kt * 32 + quad * 8 + j;
                float wv = 0.f;
                if (av) {
                    if (k >= 1 && k <= 50) wv = W_ih2[r * 50 + k - 1];
                    else if (k == 51) wv = b_ih2[r] + b_hh2[r];
                    else if (k >= 52 && k <= 101) wv = W_hh2[r * 50 + k - 52];
                }
                th[j] = f16bits(wv * sc);
            }
            a2[kt] = __builtin_bit_cast(f16x8, th);
        }
    }

    __syncthreads();
    if (tid < NB) {
        v[0][vidx(0, tid)] = xs[0 * NB + tid];           // x(0), already f16
        const unsigned short one = f16bits(1.0f);        // bias row, both bufs
        v[0][vidx(51, tid)] = one;
        v[1][vidx(51, tid)] = one;
    }
    __syncthreads();

    // ---- precomputed LDS access pointers (one base VGPR + imm offsets) ----
    const f16x8* vr0 = (const f16x8*)(&v[0][0]) + L;   // bfr base, buf 0
    const f16x8* vr1 = (const f16x8*)(&v[1][0]) + L;   // bfr base, buf 1
    unsigned short* hw0 = &v[0][hslot];                // h write, buf 0
    unsigned short* hw1 = &v[1][hslot];                // h write, buf 1
    unsigned short* xp0 = &v[0][vidx(0, xb & 7)];      // x write, buf 0
    unsigned short* xp1 = &v[1][vidx(0, xb & 7)];      // x write, buf 1

    f16x8 bfr[4];
    #pragma unroll
    for (int kt = 0; kt < 4; ++kt)
        bfr[kt] = __builtin_bit_cast(f16x8, ushort8{0,0,0,0,0,0,0,0});

    const f32x4 zacc = {0.f, 0.f, 0.f, 0.f};  // loop-invariant MFMA C operand

    // one step: iter t = L1 gates(t) + L2 gates(t-1); read vrL, write hw/xp.
    // Accumulators hold -g*log2e (g rows: -2g*log2e) -> raw v_exp gives e^-g.
    auto body = [&](int t, const f16x8* vrL, unsigned short* hw,
                    unsigned short* xp, bool doL1, bool doL2,
                    bool masked, bool doX) {
        if (doX && xw) *xp = xs[(t + 1) * NB + xb];
        if (ldB) {
            #pragma unroll
            for (int kt = 0; kt < 4; ++kt)
                bfr[kt] = vrL[kt * 64];
        }
        __builtin_amdgcn_s_setprio(1);   // favor waves still in read+MFMA front
        f32x4 aM1 = zacc, aM2 = zacc;
        if (doL2) {     // longer chain (4 dependent, C-forwarded: free) first
            #pragma unroll
            for (int kt = 0; kt < 4; ++kt)
                aM2 = __builtin_amdgcn_mfma_f32_16x16x32_f16(a2[kt], bfr[kt], aM2, 0, 0, 0);
        }
        if (doL1) {
            #pragma unroll
            for (int kt = 0; kt < 2; ++kt)
                aM1 = __builtin_amdgcn_mfma_f32_16x16x32_f16(a1[kt], bfr[kt], aM1, 0, 0, 0);
        }
        __builtin_amdgcn_s_setprio(0);   // trans section runs at base prio
        // merge: low 8 of each 16-row keep L1 acc, high 8 take partner L2 acc
        f32x4 g;
        #pragma unroll
        for (int r = 0; r < 4; ++r) g[r] = dpp_merge(aM1[r], aM2[r]);

        // cell update: g = (-i, -f, -2gg, -o)*log2e (bias included).
        // cs carries -2log2e*c, so ecn = exp2(cs) with no scaling mul.
        if (!masked || (updOK && low)) {
            float ei = exp2f_hw(g[0]);           // e^-i
            float ef = exp2f_hw(g[1]);           // e^-f
            float eg = exp2f_hw(g[2]);           // e^-2gg
            float eo = exp2f_hw(g[3]);           // e^-o
            float ti  = 1.0f + ei;
            float p   = fmaf(ti, eg, ti);        // (1+ei)(1+eg)
            float sgs = fmaf(P2LOG2E, eg, N2LOG2E); // -2log2e*(1-eg)
            float qs  = fmaf(sgs, ef, sgs);      // -2log2e*(1-eg)(1+ef)
            float uu  = 1.0f + ef;
            cs = fmaf(cs, p, qs) * fast_rcp(p * uu); // -2log2e * c_new
            float ecn = exp2f_hw(cs);            // e^-2c
            float to  = 1.0f + eo;
            float den = fmaf(to, ecn, to);       // (1+eo)(1+ecn)
            float h = (1.0f - ecn) * fast_rcp(den);
            *hw = f16bits(h);
        }
        __syncthreads();
    };

    // peel t=0 (no L2 yet: masked update protects high-half cs), steady,
    // then last-x step (t=TT-2 writes x(TT-1)), no-x step, L2-only tail.
    body(0, vr0, hw1, xp1, true, false, true,  true);
    body(1, vr1, hw0, xp0, true, true,  false, true);
    for (int t = 2; t < TT - 2; t += 2) {
        body(t,     vr0, hw1, xp1, true, true, false, true);
        body(t + 1, vr1, hw0, xp0, true, true, false, true);
    }
    body(TT - 2, vr0, hw1, xp1, true,  true, false, true);   // writes x(TT-1)
    body(TT - 1, vr1, hw0, xp0, true,  true, false, false);
    body(TT,     vr0, hw1, xp1, false, true, false, false);  // L2-only tail

    // epilogue: h2(T-1) sits in buf1 slots 52..101
    if (tid < NB) {
        float s = b_lin[0];
        #pragma unroll
        for (int uu = 0; uu < HH; ++uu)
            s += W_lin[uu] * f16tof(v[1][vidx(52 + uu, tid)]);
        out[b0g + tid] = s;
    }
}

extern "C" void kernel_launch(void* const* d_in, const int* in_sizes, int n_in,
                              void* d_out, int out_size, void* d_ws, size_t ws_size,
                              hipStream_t stream) {
    const float* x     = (const float*)d_in[0];
    const float* W_ih1 = (const float*)d_in[1];
    const float* W_hh1 = (const float*)d_in[2];
    const float* b_ih1 = (const float*)d_in[3];
    const float* b_hh1 = (const float*)d_in[4];
    const float* W_ih2 = (const float*)d_in[5];
    const float* W_hh2 = (const float*)d_in[6];
    const float* b_ih2 = (const float*)d_in[7];
    const float* b_hh2 = (const float*)d_in[8];
    const float* W_lin = (const float*)d_in[9];
    const float* b_lin = (const float*)d_in[10];
    float* out = (float*)d_out;

    const int Btot = in_sizes[0] / TT;   // 2048
    const int nblocks = Btot / NB;       // 256 -> 1 block/CU

    lstm_kernel<<<nblocks, NT, 0, stream>>>(
        x, W_ih1, W_hh1, b_ih1, b_hh1, W_ih2, W_hh2, b_ih2, b_hh2,
        W_lin, b_lin, out);
}